// Round 10
// baseline (161.655 us; speedup 1.0000x reference)
//
#include <hip/hip_runtime.h>

// SwitchTransformers sparse MLP (top-1 MoE), MI355X/gfx950.
// Round 10: GEMM re-tiled 256x256 -> 128x128 (4 waves, per-wave 64x64),
// ring-4 counted-vmcnt ledger unchanged. 64KB LDS -> 2 blocks/CU and ~790
// live blocks -> cross-block LDS/MFMA anti-phase overlap (was 1 block/CU,
// 204 blocks, phase-locked pipes). TM granule 256->128. convT/router/scan
// byte-identical to round 9.

typedef __attribute__((ext_vector_type(4))) float f32x4;
typedef __attribute__((ext_vector_type(8))) short short8;
typedef unsigned short ushort_t;
typedef unsigned int uint32;

#define DEVFN static __device__ __forceinline__
#define MFMA __builtin_amdgcn_mfma_f32_16x16x32_bf16

constexpr int NTOK = 4096;
constexpr int DM   = 768;
constexpr int DF   = 3072;
constexpr int NE   = 8;
constexpr int TM   = 128;                  // row-tile granule
constexpr int MAXTILES = NTOK / TM + NE;   // 40
constexpr int MAXR  = MAXTILES * TM;       // 5120
constexpr int BK    = 32;
constexpr int NKT   = 768 / BK;            // 24 K-steps per (split-)GEMM

// meta ints: [8..15] segStart, [16..23] seg_end, [24] nTiles,
// [64..103] tileExpert, [128..167] tileRow
DEVFN ushort_t f2bf(float f) {
  uint32 u = __float_as_uint(f);
  u += 0x7fffu + ((u >> 16) & 1u);
  return (ushort_t)(u >> 16);
}
DEVFN float bf2f(ushort_t u) { return __uint_as_float((uint32)u << 16); }

DEVFN void gl16(const void* g, void* l) {   // 16B/lane direct-to-LDS
  __builtin_amdgcn_global_load_lds(
      (const __attribute__((address_space(1))) void*)g,
      (__attribute__((address_space(3))) void*)l, 16, 0, 0);
}

// One wave per token: fp64 logits (argmax robustness), fp32 softmax
// computed redundantly on all lanes (no divergent fp64 exp, no atomics).
__global__ __launch_bounds__(256) void k_router(
    const float* __restrict__ X, const float* __restrict__ Wr,
    float* __restrict__ out_logits, float* __restrict__ out_idx,
    int* __restrict__ expert_of, float* __restrict__ prob) {
  int wid = threadIdx.x >> 6, lane = threadIdx.x & 63;
  int t = blockIdx.x * 4 + wid;
  const float* xrow = X + (size_t)t * DM;
  double acc[NE];
#pragma unroll
  for (int e = 0; e < NE; e++) acc[e] = 0.0;
  for (int d0 = 0; d0 < DM; d0 += 64) {
    int d = d0 + lane;
    float x = xrow[d];
    const float4* w4 = (const float4*)(Wr + (size_t)d * NE);
    float4 wa = w4[0], wb = w4[1];
    acc[0] += (double)x * wa.x; acc[1] += (double)x * wa.y;
    acc[2] += (double)x * wa.z; acc[3] += (double)x * wa.w;
    acc[4] += (double)x * wb.x; acc[5] += (double)x * wb.y;
    acc[6] += (double)x * wb.z; acc[7] += (double)x * wb.w;
  }
#pragma unroll
  for (int e = 0; e < NE; e++) {
#pragma unroll
    for (int s = 32; s > 0; s >>= 1) acc[e] += __shfl_xor(acc[e], s);
  }
#pragma unroll
  for (int e = 0; e < NE; e++)
    if (lane == e) out_logits[(size_t)t * NE + e] = (float)acc[e];
  double m = acc[0]; int idx = 0;
#pragma unroll
  for (int e = 1; e < NE; e++) if (acc[e] > m) { m = acc[e]; idx = e; }
  float s = 0.f;
#pragma unroll
  for (int e = 0; e < NE; e++) s += expf((float)(acc[e] - m));
  if (lane == 0) {
    out_idx[t] = (float)idx;
    expert_of[t] = idx;
    prob[t] = 1.f / s;
  }
}

// Single-block scan: per-group counts, per-expert exclusive scan, padded
// segment layout + tile table, stable-order scatter. Deterministic.
__global__ __launch_bounds__(64) void k_scan(
    const int* __restrict__ expert_of, const float* __restrict__ prob,
    int* __restrict__ meta, int* __restrict__ perm,
    float* __restrict__ prob_g) {
  __shared__ int exl[NTOK];
  int lane = threadIdx.x;
  const int4* src = (const int4*)expert_of;
  int4* dst = (int4*)exl;
#pragma unroll
  for (int j = 0; j < NTOK / 4 / 64; j++) dst[j * 64 + lane] = src[j * 64 + lane];
  __syncthreads();
  int cnt[NE];
#pragma unroll
  for (int e = 0; e < NE; e++) cnt[e] = 0;
  for (int j = 0; j < 64; j++) {
    int ex = exl[lane * 64 + j];
#pragma unroll
    for (int e = 0; e < NE; e++) cnt[e] += (ex == e);
  }
  int base[NE], tot[NE];
#pragma unroll
  for (int e = 0; e < NE; e++) {
    int inc = cnt[e];
#pragma unroll
    for (int s = 1; s < 64; s <<= 1) {
      int o = __shfl_up(inc, s);
      if (lane >= s) inc += o;
    }
    base[e] = inc - cnt[e];
    tot[e] = __shfl(inc, 63);
  }
  int segStart[NE];
  int pos = 0, nt = 0;
#pragma unroll
  for (int e = 0; e < NE; e++) {
    segStart[e] = pos;
    int tiles = (tot[e] + TM - 1) / TM;
    if (lane == 0) {
      meta[8 + e] = pos;
      meta[16 + e] = pos + tot[e];
      for (int i = 0; i < tiles; i++) {
        meta[64 + nt + i] = e;
        meta[128 + nt + i] = pos + i * TM;
      }
    }
    nt += tiles;
    pos += tiles * TM;
  }
  if (lane == 0) meta[24] = nt;
  int cum[NE];
#pragma unroll
  for (int e = 0; e < NE; e++) cum[e] = segStart[e] + base[e];
  for (int j = 0; j < 64; j++) {
    int t = lane * 64 + j;
    int ex = exl[lane * 64 + j];
    int p = 0;
#pragma unroll
    for (int e = 0; e < NE; e++) p += (ex == e) ? cum[e] : 0;
#pragma unroll
    for (int e = 0; e < NE; e++) cum[e] += (ex == e);
    perm[p] = t;
    prob_g[p] = prob[t];
  }
}

// Destination-indexed gather: Xg[r] = bf16(X[perm[r]]) for valid rows.
// Grid: (TM/4, MAXTILES) — tile on the slow dim (live-compact).
__global__ __launch_bounds__(256) void k_copy(
    const float* __restrict__ X, const int* __restrict__ meta,
    const int* __restrict__ perm, ushort_t* __restrict__ Xg) {
  int bt = blockIdx.y;
  if (bt >= meta[24]) return;
  int e = meta[64 + bt], row0 = meta[128 + bt], segEnd = meta[16 + e];
  int wid = threadIdx.x >> 6, lane = threadIdx.x & 63;
  int r = row0 + blockIdx.x * 4 + wid;
  if (r >= segEnd) return;
  int tok = perm[r];
  const float2* s2 = (const float2*)(X + (size_t)tok * DM);
  uint32* d2 = (uint32*)(Xg + (size_t)r * DM);
#pragma unroll
  for (int i = 0; i < DM / 128; i++) {
    float2 v = s2[i * 64 + lane];
    d2[i * 64 + lane] = (uint32)f2bf(v.x) | ((uint32)f2bf(v.y) << 16);
  }
}

// Convert + transpose: W [E][R][C] fp32 -> WT [E][C][R] bf16. 128x128 tile.
// Reads: 2 full 512B rows per wave-instr. LDS: T[c] row of 16 chunks, chunk
// XOR-swizzled (phys = q ^ (c&15)) -> bijective, b128-aligned. Writes: 4
// full 256B output rows per wave-instr.
__global__ __launch_bounds__(256) void k_convT(
    const float* __restrict__ W, ushort_t* __restrict__ WT, int R, int C) {
  __shared__ ushort_t T[128 * 128];
  int e = blockIdx.z;
  int r0 = blockIdx.x * 128, c0 = blockIdx.y * 128;
  const float* src = W + ((size_t)e * R + r0) * C + c0;
  int t = threadIdx.x;
  int rr = t >> 5, cc = (t & 31) * 4;
#pragma unroll
  for (int j = 0; j < 16; j++) {
    int r = rr + j * 8;
    float4 v = *(const float4*)(src + (size_t)r * C + cc);
#pragma unroll
    for (int i = 0; i < 4; i++) {
      int c = cc + i;
      T[c * 128 + (((r >> 3) ^ (c & 15)) << 3) + (r & 7)] =
          f2bf(((const float*)&v)[i]);
    }
  }
  __syncthreads();
  int q = t & 15, cb = t >> 4;
#pragma unroll
  for (int j = 0; j < 8; j++) {
    int c = cb + j * 16;
    short8 v = *(const short8*)&T[c * 128 + ((q ^ (c & 15)) << 3)];
    *(short8*)(WT + ((size_t)e * C + c0 + c) * R + r0 + q * 8) = v;
  }
}

// ---------------------------------------------------------------------------
// 4-wave 128x128 GEMM, BK=32, ring-4 LDS slots (64 KB -> 2 blocks/CU),
// counted vmcnt(8), 1 barrier per K-step, XOR bank swizzle. Per-wave output
// 64x64 (wave grid 2Mx2N), acc[4][4] f32x4, 16 MFMA + 8 ds_read_b128 per
// K-step. Grid: y = row-tile (slow dim, live-compact).
// FIRST: x = N-panel. !FIRST: x = panel*4 + z (split-K, koff = z*768).
// ---------------------------------------------------------------------------
template <int LDA, int NB, bool FIRST>
__global__ __launch_bounds__(256, 2) void k_gemm8(
    const ushort_t* __restrict__ A, const ushort_t* __restrict__ BT,
    const int* __restrict__ meta, ushort_t* __restrict__ Obf) {
  __shared__ short A_lds[4][128 * BK];
  __shared__ short B_lds[4][128 * BK];

  int bt = blockIdx.y;
  if (bt >= meta[24]) return;      // uniform exit before any barrier
  int e    = meta[64 + bt];
  int row0 = meta[128 + bt];
  int n0, koff, z;
  if constexpr (FIRST) {
    n0 = blockIdx.x * 128; koff = 0; z = 0;
  } else {
    n0 = (blockIdx.x >> 2) * 128; z = blockIdx.x & 3; koff = z * 768;
  }

  int tid = threadIdx.x, lane = tid & 63, w = tid >> 6;
  int wr = w >> 1, wc = w & 1;

  // Staging: thread -> row tid>>2 (0..63; +64 for second issue), 16B slot
  // tid&3 (linear LDS dest); global source pre-swizzled:
  // kslot_log = (lane&3) ^ ((lane>>3)&3)  [row = w*16 + (lane>>2), and
  // (row>>1)&3 == (lane>>3)&3 since w*8 ≡ 0 mod 4].
  int srcSlot = (lane & 3) ^ ((lane >> 3) & 3);
  const ushort_t* aS = A + (size_t)(row0 + (tid >> 2)) * LDA + koff + srcSlot * 8;
  const ushort_t* bS = BT + ((size_t)e * NB + n0 + (tid >> 2)) * LDA + koff + srcSlot * 8;
  int dstOff = w * 512;   // wave-uniform LDS short offset (16 rows/wave/issue)

#define STAGE(sl, kt)                                                        \
  do {                                                                       \
    gl16(aS + (size_t)(kt) * BK, &A_lds[sl][dstOff]);                        \
    gl16(aS + (size_t)(kt) * BK + (size_t)64 * LDA, &A_lds[sl][dstOff + 2048]); \
    gl16(bS + (size_t)(kt) * BK, &B_lds[sl][dstOff]);                        \
    gl16(bS + (size_t)(kt) * BK + (size_t)64 * LDA, &B_lds[sl][dstOff + 2048]); \
  } while (0)

  // Swizzled read offsets: physical kslot = logical ^ ((row>>1)&3).
  int kslotRd = ((lane >> 4) ^ ((lane >> 1) & 3)) * 8;
  int aOff[4], bOff[4];
#pragma unroll
  for (int m = 0; m < 4; m++)
    aOff[m] = (wr * 64 + m * 16 + (lane & 15)) * BK + kslotRd;
#pragma unroll
  for (int n = 0; n < 4; n++)
    bOff[n] = (wc * 64 + n * 16 + (lane & 15)) * BK + kslotRd;

  f32x4 acc[4][4];
#pragma unroll
  for (int m = 0; m < 4; m++)
#pragma unroll
    for (int n = 0; n < 4; n++) acc[m][n] = (f32x4){0.f, 0.f, 0.f, 0.f};

  STAGE(0, 0); STAGE(1, 1); STAGE(2, 2);   // 12 loads in flight

#pragma unroll 4
  for (int t = 0; t < NKT; ++t) {
    __builtin_amdgcn_sched_barrier(0);
    asm volatile("s_waitcnt vmcnt(8)" ::: "memory");  // own slot-t loads done
    __builtin_amdgcn_s_barrier();                     // all waves' slot-t done;
    asm volatile("" ::: "memory");                    // all done reading t-1
    __builtin_amdgcn_sched_barrier(0);
    int tp = (t + 3 < NKT) ? t + 3 : t;               // dummy keeps vmcnt uniform
    STAGE((t + 3) & 3, tp);                           // (dead ring slot at tail)
    const short* aB = A_lds[t & 3];
    const short* bB = B_lds[t & 3];
    short8 af[4], bf[4];
#pragma unroll
    for (int m = 0; m < 4; m++) af[m] = *(const short8*)&aB[aOff[m]];
#pragma unroll
    for (int n = 0; n < 4; n++) bf[n] = *(const short8*)&bB[bOff[n]];
    __builtin_amdgcn_s_setprio(1);
#pragma unroll
    for (int m = 0; m < 4; m++)
#pragma unroll
      for (int n = 0; n < 4; n++)
        acc[m][n] = MFMA(af[m], bf[n], acc[m][n], 0, 0, 0);
    __builtin_amdgcn_s_setprio(0);
  }
#undef STAGE

  // C/D: col = lane&15, row = (lane>>4)*4 + r
  ushort_t* dst = FIRST ? Obf : Obf + (size_t)z * MAXR * NB;
#pragma unroll
  for (int m = 0; m < 4; m++) {
    int rowb = row0 + wr * 64 + m * 16 + (lane >> 4) * 4;
#pragma unroll
    for (int n = 0; n < 4; n++) {
      int col = n0 + wc * 64 + n * 16 + (lane & 15);
#pragma unroll
      for (int r = 0; r < 4; r++) {
        float v = acc[m][n][r];
        if (FIRST) v = v > 0.f ? v : 0.f;
        dst[(size_t)(rowb + r) * NB + col] = f2bf(v);
      }
    }
  }
}

// Reduce split-K partials, scale by prob, scatter to token rows.
// Grid: (DM/64, MAXTILES) — tile on the slow dim (live-compact).
__global__ __launch_bounds__(256) void k_reduce(
    const ushort_t* __restrict__ P, const int* __restrict__ meta,
    const int* __restrict__ perm, const float* __restrict__ prob_g,
    float* __restrict__ out) {
  int bt = blockIdx.y;
  if (bt >= meta[24]) return;
  int e = meta[64 + bt], row0 = meta[128 + bt], segEnd = meta[16 + e];
  int c0 = blockIdx.x * 64;
  int t = threadIdx.x;
  int col = c0 + (t & 7) * 8;
#pragma unroll
  for (int i = 0; i < 4; i++) {
    int r = row0 + (t >> 3) + i * 32;
    if (r >= segEnd) continue;
    int tok = perm[r];
    float p = prob_g[r];
    float s[8];
#pragma unroll
    for (int j = 0; j < 8; j++) s[j] = 0.f;
#pragma unroll
    for (int z = 0; z < 4; z++) {
      short8 v = *(const short8*)&P[((size_t)z * MAXR + r) * DM + col];
#pragma unroll
      for (int j = 0; j < 8; j++) s[j] += bf2f((ushort_t)v[j]);
    }
    float4 o0 = {p * s[0], p * s[1], p * s[2], p * s[3]};
    float4 o1 = {p * s[4], p * s[5], p * s[6], p * s[7]};
    *(float4*)&out[(size_t)tok * DM + col] = o0;
    *(float4*)&out[(size_t)tok * DM + col + 4] = o1;
  }
}

extern "C" void kernel_launch(void* const* d_in, const int* in_sizes, int n_in,
                              void* d_out, int out_size, void* d_ws, size_t ws_size,
                              hipStream_t stream) {
  const float* X  = (const float*)d_in[0];
  const float* Wr = (const float*)d_in[1];
  const float* wi = (const float*)d_in[2];
  const float* wo = (const float*)d_in[3];

  float* out        = (float*)d_out;
  float* out_logits = out + (size_t)NTOK * DM;
  float* out_idx    = out_logits + (size_t)NTOK * NE;

  char* w = (char*)d_ws;
  int*      meta      = (int*)w;                    // 4 KiB
  int*      expert_of = (int*)(w + 4096);           // 16 KiB
  float*    prob      = (float*)(w + 20480);        // 16 KiB
  int*      perm      = (int*)(w + 36864);          // 24 KiB
  float*    prob_g    = (float*)(w + 61440);        // 24 KiB
  ushort_t* Xg        = (ushort_t*)(w + 131072);    // 5120*768 bf16
  ushort_t* H         = Xg + (size_t)MAXR * DM;     // 5120*3072 bf16
  ushort_t* woT       = H + (size_t)MAXR * DF;      // 8*768*3072 bf16
  ushort_t* wiT       = woT + (size_t)NE * DM * DF; // 8*3072*768 bf16
  ushort_t* P         = wiT;                        // alias: wiT dead after
                                                    // GEMM1; P = 4*5120*768*2
                                                    // = 62.9 MB (extends past
                                                    // wiT into free ws)
  // total ws ~ 180 MB

  k_convT<<<dim3(DM / 128, DF / 128, NE), 256, 0, stream>>>(wi, wiT, DM, DF);
  k_convT<<<dim3(DF / 128, DM / 128, NE), 256, 0, stream>>>(wo, woT, DF, DM);
  k_router<<<NTOK / 4, 256, 0, stream>>>(X, Wr, out_logits, out_idx,
                                         expert_of, prob);
  k_scan<<<1, 64, 0, stream>>>(expert_of, prob, meta, perm, prob_g);
  k_copy<<<dim3(TM / 4, MAXTILES), 256, 0, stream>>>(X, meta, perm, Xg);
  k_gemm8<DM, DF, true><<<dim3(DF / 128, MAXTILES), 256, 0, stream>>>(
      Xg, wiT, meta, H);
  k_gemm8<DF, DM, false><<<dim3((DM / 128) * 4, MAXTILES), 256, 0, stream>>>(
      H, woT, meta, P);
  k_reduce<<<dim3(DM / 64, MAXTILES), 256, 0, stream>>>(P, meta, perm, prob_g, out);
}

// Round 11
// 159.811 us; speedup vs baseline: 1.0115x; 1.0115x over previous
//
#include <hip/hip_runtime.h>

// SwitchTransformers sparse MLP (top-1 MoE), MI355X/gfx950.
// Round 11: ring-3 LDS (48KB -> 3 blocks/CU = 12 waves/CU, m97 occupancy),
// counted vmcnt(4) + peeled vmcnt(0) final step, stage-2-ahead. GEMM2
// split-K 4->2 (halves P traffic + reduce). Everything else unchanged.

typedef __attribute__((ext_vector_type(4))) float f32x4;
typedef __attribute__((ext_vector_type(8))) short short8;
typedef unsigned short ushort_t;
typedef unsigned int uint32;

#define DEVFN static __device__ __forceinline__
#define MFMA __builtin_amdgcn_mfma_f32_16x16x32_bf16

constexpr int NTOK = 4096;
constexpr int DM   = 768;
constexpr int DF   = 3072;
constexpr int NE   = 8;
constexpr int TM   = 128;                  // row-tile granule
constexpr int MAXTILES = NTOK / TM + NE;   // 40
constexpr int MAXR  = MAXTILES * TM;       // 5120
constexpr int BK    = 32;
constexpr int KS2   = 2;                   // GEMM2 split-K

// meta ints: [8..15] segStart, [16..23] seg_end, [24] nTiles,
// [64..103] tileExpert, [128..167] tileRow
DEVFN ushort_t f2bf(float f) {
  uint32 u = __float_as_uint(f);
  u += 0x7fffu + ((u >> 16) & 1u);
  return (ushort_t)(u >> 16);
}
DEVFN float bf2f(ushort_t u) { return __uint_as_float((uint32)u << 16); }

DEVFN void gl16(const void* g, void* l) {   // 16B/lane direct-to-LDS
  __builtin_amdgcn_global_load_lds(
      (const __attribute__((address_space(1))) void*)g,
      (__attribute__((address_space(3))) void*)l, 16, 0, 0);
}

// One wave per token: fp64 logits (argmax robustness), fp32 softmax
// computed redundantly on all lanes (no divergent fp64 exp, no atomics).
__global__ __launch_bounds__(256) void k_router(
    const float* __restrict__ X, const float* __restrict__ Wr,
    float* __restrict__ out_logits, float* __restrict__ out_idx,
    int* __restrict__ expert_of, float* __restrict__ prob) {
  int wid = threadIdx.x >> 6, lane = threadIdx.x & 63;
  int t = blockIdx.x * 4 + wid;
  const float* xrow = X + (size_t)t * DM;
  double acc[NE];
#pragma unroll
  for (int e = 0; e < NE; e++) acc[e] = 0.0;
  for (int d0 = 0; d0 < DM; d0 += 64) {
    int d = d0 + lane;
    float x = xrow[d];
    const float4* w4 = (const float4*)(Wr + (size_t)d * NE);
    float4 wa = w4[0], wb = w4[1];
    acc[0] += (double)x * wa.x; acc[1] += (double)x * wa.y;
    acc[2] += (double)x * wa.z; acc[3] += (double)x * wa.w;
    acc[4] += (double)x * wb.x; acc[5] += (double)x * wb.y;
    acc[6] += (double)x * wb.z; acc[7] += (double)x * wb.w;
  }
#pragma unroll
  for (int e = 0; e < NE; e++) {
#pragma unroll
    for (int s = 32; s > 0; s >>= 1) acc[e] += __shfl_xor(acc[e], s);
  }
#pragma unroll
  for (int e = 0; e < NE; e++)
    if (lane == e) out_logits[(size_t)t * NE + e] = (float)acc[e];
  double m = acc[0]; int idx = 0;
#pragma unroll
  for (int e = 1; e < NE; e++) if (acc[e] > m) { m = acc[e]; idx = e; }
  float s = 0.f;
#pragma unroll
  for (int e = 0; e < NE; e++) s += expf((float)(acc[e] - m));
  if (lane == 0) {
    out_idx[t] = (float)idx;
    expert_of[t] = idx;
    prob[t] = 1.f / s;
  }
}

// Single-block scan: per-group counts, per-expert exclusive scan, padded
// segment layout + tile table, stable-order scatter. Deterministic.
__global__ __launch_bounds__(64) void k_scan(
    const int* __restrict__ expert_of, const float* __restrict__ prob,
    int* __restrict__ meta, int* __restrict__ perm,
    float* __restrict__ prob_g) {
  __shared__ int exl[NTOK];
  int lane = threadIdx.x;
  const int4* src = (const int4*)expert_of;
  int4* dst = (int4*)exl;
#pragma unroll
  for (int j = 0; j < NTOK / 4 / 64; j++) dst[j * 64 + lane] = src[j * 64 + lane];
  __syncthreads();
  int cnt[NE];
#pragma unroll
  for (int e = 0; e < NE; e++) cnt[e] = 0;
  for (int j = 0; j < 64; j++) {
    int ex = exl[lane * 64 + j];
#pragma unroll
    for (int e = 0; e < NE; e++) cnt[e] += (ex == e);
  }
  int base[NE], tot[NE];
#pragma unroll
  for (int e = 0; e < NE; e++) {
    int inc = cnt[e];
#pragma unroll
    for (int s = 1; s < 64; s <<= 1) {
      int o = __shfl_up(inc, s);
      if (lane >= s) inc += o;
    }
    base[e] = inc - cnt[e];
    tot[e] = __shfl(inc, 63);
  }
  int segStart[NE];
  int pos = 0, nt = 0;
#pragma unroll
  for (int e = 0; e < NE; e++) {
    segStart[e] = pos;
    int tiles = (tot[e] + TM - 1) / TM;
    if (lane == 0) {
      meta[8 + e] = pos;
      meta[16 + e] = pos + tot[e];
      for (int i = 0; i < tiles; i++) {
        meta[64 + nt + i] = e;
        meta[128 + nt + i] = pos + i * TM;
      }
    }
    nt += tiles;
    pos += tiles * TM;
  }
  if (lane == 0) meta[24] = nt;
  int cum[NE];
#pragma unroll
  for (int e = 0; e < NE; e++) cum[e] = segStart[e] + base[e];
  for (int j = 0; j < 64; j++) {
    int t = lane * 64 + j;
    int ex = exl[lane * 64 + j];
    int p = 0;
#pragma unroll
    for (int e = 0; e < NE; e++) p += (ex == e) ? cum[e] : 0;
#pragma unroll
    for (int e = 0; e < NE; e++) cum[e] += (ex == e);
    perm[p] = t;
    prob_g[p] = prob[t];
  }
}

// Destination-indexed gather: Xg[r] = bf16(X[perm[r]]) for valid rows.
// Grid: (TM/4, MAXTILES) — tile on the slow dim (live-compact).
__global__ __launch_bounds__(256) void k_copy(
    const float* __restrict__ X, const int* __restrict__ meta,
    const int* __restrict__ perm, ushort_t* __restrict__ Xg) {
  int bt = blockIdx.y;
  if (bt >= meta[24]) return;
  int e = meta[64 + bt], row0 = meta[128 + bt], segEnd = meta[16 + e];
  int wid = threadIdx.x >> 6, lane = threadIdx.x & 63;
  int r = row0 + blockIdx.x * 4 + wid;
  if (r >= segEnd) return;
  int tok = perm[r];
  const float2* s2 = (const float2*)(X + (size_t)tok * DM);
  uint32* d2 = (uint32*)(Xg + (size_t)r * DM);
#pragma unroll
  for (int i = 0; i < DM / 128; i++) {
    float2 v = s2[i * 64 + lane];
    d2[i * 64 + lane] = (uint32)f2bf(v.x) | ((uint32)f2bf(v.y) << 16);
  }
}

// Convert + transpose: W [E][R][C] fp32 -> WT [E][C][R] bf16. 128x128 tile.
__global__ __launch_bounds__(256) void k_convT(
    const float* __restrict__ W, ushort_t* __restrict__ WT, int R, int C) {
  __shared__ ushort_t T[128 * 128];
  int e = blockIdx.z;
  int r0 = blockIdx.x * 128, c0 = blockIdx.y * 128;
  const float* src = W + ((size_t)e * R + r0) * C + c0;
  int t = threadIdx.x;
  int rr = t >> 5, cc = (t & 31) * 4;
#pragma unroll
  for (int j = 0; j < 16; j++) {
    int r = rr + j * 8;
    float4 v = *(const float4*)(src + (size_t)r * C + cc);
#pragma unroll
    for (int i = 0; i < 4; i++) {
      int c = cc + i;
      T[c * 128 + (((r >> 3) ^ (c & 15)) << 3) + (r & 7)] =
          f2bf(((const float*)&v)[i]);
    }
  }
  __syncthreads();
  int q = t & 15, cb = t >> 4;
#pragma unroll
  for (int j = 0; j < 8; j++) {
    int c = cb + j * 16;
    short8 v = *(const short8*)&T[c * 128 + ((q ^ (c & 15)) << 3)];
    *(short8*)(WT + ((size_t)e * C + c0 + c) * R + r0 + q * 8) = v;
  }
}

// ---------------------------------------------------------------------------
// 4-wave 128x128 GEMM, BK=32, ring-3 LDS slots (48 KB -> 3 blocks/CU),
// stage-2-ahead, counted vmcnt(4) (final step vmcnt(0)), 1 barrier/K-step,
// XOR bank swizzle. Per-wave 64x64 (2Mx2N waves), 16 MFMA + 8 ds_read_b128
// per wave-K-step. Grid: y = row-tile (slow dim, live-compact).
// FIRST: x = N-panel, K = LDA. !FIRST: x = panel*KS2 + z, koff = z*LDA/KS2.
// ---------------------------------------------------------------------------
template <int LDA, int NB, int KSPLIT, bool FIRST>
__global__ __launch_bounds__(256, 3) void k_gemm8(
    const ushort_t* __restrict__ A, const ushort_t* __restrict__ BT,
    const int* __restrict__ meta, ushort_t* __restrict__ Obf) {
  constexpr int NKTT = LDA / KSPLIT / BK;
  __shared__ short A_lds[3][128 * BK];
  __shared__ short B_lds[3][128 * BK];

  int bt = blockIdx.y;
  if (bt >= meta[24]) return;      // uniform exit before any barrier
  int e    = meta[64 + bt];
  int row0 = meta[128 + bt];
  int n0, koff, z;
  if constexpr (FIRST) {
    n0 = blockIdx.x * 128; koff = 0; z = 0;
  } else {
    n0 = (blockIdx.x / KSPLIT) * 128; z = blockIdx.x % KSPLIT;
    koff = z * (LDA / KSPLIT);
  }

  int tid = threadIdx.x, lane = tid & 63, w = tid >> 6;
  int wr = w >> 1, wc = w & 1;

  // Staging: thread -> row tid>>2 (+64 second issue), 16B slot tid&3
  // (linear LDS dest); global source pre-swizzled:
  // kslot_log = (lane&3) ^ ((lane>>3)&3).
  int srcSlot = (lane & 3) ^ ((lane >> 3) & 3);
  const ushort_t* aS = A + (size_t)(row0 + (tid >> 2)) * LDA + koff + srcSlot * 8;
  const ushort_t* bS = BT + ((size_t)e * NB + n0 + (tid >> 2)) * LDA + koff + srcSlot * 8;
  int dstOff = w * 512;   // wave-uniform LDS short offset (16 rows/wave/issue)

#define STAGE(sl, kt)                                                        \
  do {                                                                       \
    gl16(aS + (size_t)(kt) * BK, &A_lds[sl][dstOff]);                        \
    gl16(aS + (size_t)(kt) * BK + (size_t)64 * LDA, &A_lds[sl][dstOff + 2048]); \
    gl16(bS + (size_t)(kt) * BK, &B_lds[sl][dstOff]);                        \
    gl16(bS + (size_t)(kt) * BK + (size_t)64 * LDA, &B_lds[sl][dstOff + 2048]); \
  } while (0)

  // Swizzled read offsets: physical kslot = logical ^ ((row>>1)&3).
  int kslotRd = ((lane >> 4) ^ ((lane >> 1) & 3)) * 8;
  int aOff[4], bOff[4];
#pragma unroll
  for (int m = 0; m < 4; m++)
    aOff[m] = (wr * 64 + m * 16 + (lane & 15)) * BK + kslotRd;
#pragma unroll
  for (int n = 0; n < 4; n++)
    bOff[n] = (wc * 64 + n * 16 + (lane & 15)) * BK + kslotRd;

  f32x4 acc[4][4];
#pragma unroll
  for (int m = 0; m < 4; m++)
#pragma unroll
    for (int n = 0; n < 4; n++) acc[m][n] = (f32x4){0.f, 0.f, 0.f, 0.f};

  // Ledger: stage tiles 0,1 (8 loads). Step t: vmcnt(4) retires tile t
  // (tile t+1 stays in flight); barrier; stage tile t+2 into slot (t+2)%3
  // (its readers finished at step t-1). Final step: vmcnt(0).
  STAGE(0, 0); STAGE(1, 1);

#define STEP(T, VMSTR)                                                       \
  do {                                                                       \
    __builtin_amdgcn_sched_barrier(0);                                       \
    asm volatile("s_waitcnt vmcnt(" VMSTR ")" ::: "memory");                 \
    __builtin_amdgcn_s_barrier();                                            \
    asm volatile("" ::: "memory");                                           \
    __builtin_amdgcn_sched_barrier(0);                                       \
    if ((T) + 2 < NKTT) STAGE(((T) + 2) % 3, (T) + 2);                       \
    const short* aB = A_lds[(T) % 3];                                        \
    const short* bB = B_lds[(T) % 3];                                        \
    short8 af[4], bf[4];                                                     \
    _Pragma("unroll") for (int m = 0; m < 4; m++)                            \
      af[m] = *(const short8*)&aB[aOff[m]];                                  \
    _Pragma("unroll") for (int n = 0; n < 4; n++)                            \
      bf[n] = *(const short8*)&bB[bOff[n]];                                  \
    __builtin_amdgcn_s_setprio(1);                                           \
    _Pragma("unroll") for (int m = 0; m < 4; m++)                            \
      _Pragma("unroll") for (int n = 0; n < 4; n++)                          \
        acc[m][n] = MFMA(af[m], bf[n], acc[m][n], 0, 0, 0);                  \
    __builtin_amdgcn_s_setprio(0);                                           \
  } while (0)

#pragma unroll 3
  for (int t = 0; t < NKTT - 1; ++t) STEP(t, "4");
  STEP(NKTT - 1, "0");
#undef STEP
#undef STAGE

  // C/D: col = lane&15, row = (lane>>4)*4 + r
  ushort_t* dst = FIRST ? Obf : Obf + (size_t)z * MAXR * NB;
#pragma unroll
  for (int m = 0; m < 4; m++) {
    int rowb = row0 + wr * 64 + m * 16 + (lane >> 4) * 4;
#pragma unroll
    for (int n = 0; n < 4; n++) {
      int col = n0 + wc * 64 + n * 16 + (lane & 15);
#pragma unroll
      for (int r = 0; r < 4; r++) {
        float v = acc[m][n][r];
        if (FIRST) v = v > 0.f ? v : 0.f;
        dst[(size_t)(rowb + r) * NB + col] = f2bf(v);
      }
    }
  }
}

// Reduce split-K partials, scale by prob, scatter to token rows.
// Grid: (DM/64, MAXTILES) — tile on the slow dim (live-compact).
__global__ __launch_bounds__(256) void k_reduce(
    const ushort_t* __restrict__ P, const int* __restrict__ meta,
    const int* __restrict__ perm, const float* __restrict__ prob_g,
    float* __restrict__ out) {
  int bt = blockIdx.y;
  if (bt >= meta[24]) return;
  int e = meta[64 + bt], row0 = meta[128 + bt], segEnd = meta[16 + e];
  int c0 = blockIdx.x * 64;
  int t = threadIdx.x;
  int col = c0 + (t & 7) * 8;
#pragma unroll
  for (int i = 0; i < 4; i++) {
    int r = row0 + (t >> 3) + i * 32;
    if (r >= segEnd) continue;
    int tok = perm[r];
    float p = prob_g[r];
    float s[8];
#pragma unroll
    for (int j = 0; j < 8; j++) s[j] = 0.f;
#pragma unroll
    for (int z = 0; z < KS2; z++) {
      short8 v = *(const short8*)&P[((size_t)z * MAXR + r) * DM + col];
#pragma unroll
      for (int j = 0; j < 8; j++) s[j] += bf2f((ushort_t)v[j]);
    }
    float4 o0 = {p * s[0], p * s[1], p * s[2], p * s[3]};
    float4 o1 = {p * s[4], p * s[5], p * s[6], p * s[7]};
    *(float4*)&out[(size_t)tok * DM + col] = o0;
    *(float4*)&out[(size_t)tok * DM + col + 4] = o1;
  }
}

extern "C" void kernel_launch(void* const* d_in, const int* in_sizes, int n_in,
                              void* d_out, int out_size, void* d_ws, size_t ws_size,
                              hipStream_t stream) {
  const float* X  = (const float*)d_in[0];
  const float* Wr = (const float*)d_in[1];
  const float* wi = (const float*)d_in[2];
  const float* wo = (const float*)d_in[3];

  float* out        = (float*)d_out;
  float* out_logits = out + (size_t)NTOK * DM;
  float* out_idx    = out_logits + (size_t)NTOK * NE;

  char* w = (char*)d_ws;
  int*      meta      = (int*)w;                    // 4 KiB
  int*      expert_of = (int*)(w + 4096);           // 16 KiB
  float*    prob      = (float*)(w + 20480);        // 16 KiB
  int*      perm      = (int*)(w + 36864);          // 24 KiB
  float*    prob_g    = (float*)(w + 61440);        // 24 KiB
  ushort_t* Xg        = (ushort_t*)(w + 131072);    // 5120*768 bf16
  ushort_t* H         = Xg + (size_t)MAXR * DM;     // 5120*3072 bf16
  ushort_t* woT       = H + (size_t)MAXR * DF;      // 8*768*3072 bf16
  ushort_t* wiT       = woT + (size_t)NE * DM * DF; // 8*3072*768 bf16
  ushort_t* P         = wiT;                        // alias: wiT dead after
                                                    // GEMM1; P = 2*5120*768*2
                                                    // = 15.7 MB < wiT (37.7)
  // total ws ~ 117 MB

  k_convT<<<dim3(DM / 128, DF / 128, NE), 256, 0, stream>>>(wi, wiT, DM, DF);
  k_convT<<<dim3(DF / 128, DM / 128, NE), 256, 0, stream>>>(wo, woT, DF, DM);
  k_router<<<NTOK / 4, 256, 0, stream>>>(X, Wr, out_logits, out_idx,
                                         expert_of, prob);
  k_scan<<<1, 64, 0, stream>>>(expert_of, prob, meta, perm, prob_g);
  k_copy<<<dim3(TM / 4, MAXTILES), 256, 0, stream>>>(X, meta, perm, Xg);
  k_gemm8<DM, DF, 1, true><<<dim3(DF / 128, MAXTILES), 256, 0, stream>>>(
      Xg, wiT, meta, H);
  k_gemm8<DF, DM, KS2, false><<<dim3((DM / 128) * KS2, MAXTILES), 256, 0, stream>>>(
      H, woT, meta, P);
  k_reduce<<<dim3(DM / 64, MAXTILES), 256, 0, stream>>>(P, meta, perm, prob_g, out);
}

// Round 12
// 151.119 us; speedup vs baseline: 1.0697x; 1.0575x over previous
//
#include <hip/hip_runtime.h>

// SwitchTransformers sparse MLP (top-1 MoE), MI355X/gfx950.
// Round 12: convT pass DELETED (was a 227MB/36us-floor tax). GEMMs read
// fp32 weights directly: B reg-staged (4x4 micro-tile, truncation-pack to
// bf16, in-register transpose, XOR-swizzled pad-40 LDS); A via
// global_load_lds as before. m97-style single-barrier double-buffer with
// issue-early/write-late B staging. Router/scan/copy/reduce unchanged.

typedef __attribute__((ext_vector_type(4))) float f32x4;
typedef __attribute__((ext_vector_type(8))) short short8;
typedef unsigned short ushort_t;
typedef unsigned int uint32;

#define DEVFN static __device__ __forceinline__
#define MFMA __builtin_amdgcn_mfma_f32_16x16x32_bf16

constexpr int NTOK = 4096;
constexpr int DM   = 768;
constexpr int DF   = 3072;
constexpr int NE   = 8;
constexpr int TM   = 128;                  // row-tile granule
constexpr int MAXTILES = NTOK / TM + NE;   // 40
constexpr int MAXR  = MAXTILES * TM;       // 5120
constexpr int BK    = 32;
constexpr int KS2   = 2;                   // GEMM2 split-K
constexpr int BSTR  = 40;                  // B_lds row stride (shorts), 80B

// meta ints: [8..15] segStart, [16..23] seg_end, [24] nTiles,
// [64..103] tileExpert, [128..167] tileRow
DEVFN ushort_t f2bf(float f) {           // RNE (activations)
  uint32 u = __float_as_uint(f);
  u += 0x7fffu + ((u >> 16) & 1u);
  return (ushort_t)(u >> 16);
}
DEVFN float bf2f(ushort_t u) { return __uint_as_float((uint32)u << 16); }
DEVFN uint32 pkbf(float a, float b) {    // truncating pack: bf16(a)|bf16(b)<<16
  return (__float_as_uint(b) & 0xffff0000u) | (__float_as_uint(a) >> 16);
}

DEVFN void gl16(const void* g, void* l) {   // 16B/lane direct-to-LDS
  __builtin_amdgcn_global_load_lds(
      (const __attribute__((address_space(1))) void*)g,
      (__attribute__((address_space(3))) void*)l, 16, 0, 0);
}

// One wave per token: fp64 logits (argmax robustness), fp32 softmax
// computed redundantly on all lanes (no divergent fp64 exp, no atomics).
__global__ __launch_bounds__(256) void k_router(
    const float* __restrict__ X, const float* __restrict__ Wr,
    float* __restrict__ out_logits, float* __restrict__ out_idx,
    int* __restrict__ expert_of, float* __restrict__ prob) {
  int wid = threadIdx.x >> 6, lane = threadIdx.x & 63;
  int t = blockIdx.x * 4 + wid;
  const float* xrow = X + (size_t)t * DM;
  double acc[NE];
#pragma unroll
  for (int e = 0; e < NE; e++) acc[e] = 0.0;
  for (int d0 = 0; d0 < DM; d0 += 64) {
    int d = d0 + lane;
    float x = xrow[d];
    const float4* w4 = (const float4*)(Wr + (size_t)d * NE);
    float4 wa = w4[0], wb = w4[1];
    acc[0] += (double)x * wa.x; acc[1] += (double)x * wa.y;
    acc[2] += (double)x * wa.z; acc[3] += (double)x * wa.w;
    acc[4] += (double)x * wb.x; acc[5] += (double)x * wb.y;
    acc[6] += (double)x * wb.z; acc[7] += (double)x * wb.w;
  }
#pragma unroll
  for (int e = 0; e < NE; e++) {
#pragma unroll
    for (int s = 32; s > 0; s >>= 1) acc[e] += __shfl_xor(acc[e], s);
  }
#pragma unroll
  for (int e = 0; e < NE; e++)
    if (lane == e) out_logits[(size_t)t * NE + e] = (float)acc[e];
  double m = acc[0]; int idx = 0;
#pragma unroll
  for (int e = 1; e < NE; e++) if (acc[e] > m) { m = acc[e]; idx = e; }
  float s = 0.f;
#pragma unroll
  for (int e = 0; e < NE; e++) s += expf((float)(acc[e] - m));
  if (lane == 0) {
    out_idx[t] = (float)idx;
    expert_of[t] = idx;
    prob[t] = 1.f / s;
  }
}

// Single-block scan: per-group counts, per-expert exclusive scan, padded
// segment layout + tile table, stable-order scatter. Deterministic.
__global__ __launch_bounds__(64) void k_scan(
    const int* __restrict__ expert_of, const float* __restrict__ prob,
    int* __restrict__ meta, int* __restrict__ perm,
    float* __restrict__ prob_g) {
  __shared__ int exl[NTOK];
  int lane = threadIdx.x;
  const int4* src = (const int4*)expert_of;
  int4* dst = (int4*)exl;
#pragma unroll
  for (int j = 0; j < NTOK / 4 / 64; j++) dst[j * 64 + lane] = src[j * 64 + lane];
  __syncthreads();
  int cnt[NE];
#pragma unroll
  for (int e = 0; e < NE; e++) cnt[e] = 0;
  for (int j = 0; j < 64; j++) {
    int ex = exl[lane * 64 + j];
#pragma unroll
    for (int e = 0; e < NE; e++) cnt[e] += (ex == e);
  }
  int base[NE], tot[NE];
#pragma unroll
  for (int e = 0; e < NE; e++) {
    int inc = cnt[e];
#pragma unroll
    for (int s = 1; s < 64; s <<= 1) {
      int o = __shfl_up(inc, s);
      if (lane >= s) inc += o;
    }
    base[e] = inc - cnt[e];
    tot[e] = __shfl(inc, 63);
  }
  int segStart[NE];
  int pos = 0, nt = 0;
#pragma unroll
  for (int e = 0; e < NE; e++) {
    segStart[e] = pos;
    int tiles = (tot[e] + TM - 1) / TM;
    if (lane == 0) {
      meta[8 + e] = pos;
      meta[16 + e] = pos + tot[e];
      for (int i = 0; i < tiles; i++) {
        meta[64 + nt + i] = e;
        meta[128 + nt + i] = pos + i * TM;
      }
    }
    nt += tiles;
    pos += tiles * TM;
  }
  if (lane == 0) meta[24] = nt;
  int cum[NE];
#pragma unroll
  for (int e = 0; e < NE; e++) cum[e] = segStart[e] + base[e];
  for (int j = 0; j < 64; j++) {
    int t = lane * 64 + j;
    int ex = exl[lane * 64 + j];
    int p = 0;
#pragma unroll
    for (int e = 0; e < NE; e++) p += (ex == e) ? cum[e] : 0;
#pragma unroll
    for (int e = 0; e < NE; e++) cum[e] += (ex == e);
    perm[p] = t;
    prob_g[p] = prob[t];
  }
}

// Destination-indexed gather: Xg[r] = bf16(X[perm[r]]) for valid rows.
__global__ __launch_bounds__(256) void k_copy(
    const float* __restrict__ X, const int* __restrict__ meta,
    const int* __restrict__ perm, ushort_t* __restrict__ Xg) {
  int bt = blockIdx.y;
  if (bt >= meta[24]) return;
  int e = meta[64 + bt], row0 = meta[128 + bt], segEnd = meta[16 + e];
  int wid = threadIdx.x >> 6, lane = threadIdx.x & 63;
  int r = row0 + blockIdx.x * 4 + wid;
  if (r >= segEnd) return;
  int tok = perm[r];
  const float2* s2 = (const float2*)(X + (size_t)tok * DM);
  uint32* d2 = (uint32*)(Xg + (size_t)r * DM);
#pragma unroll
  for (int i = 0; i < DM / 128; i++) {
    float2 v = s2[i * 64 + lane];
    d2[i * 64 + lane] = (uint32)f2bf(v.x) | ((uint32)f2bf(v.y) << 16);
  }
}

// ---------------------------------------------------------------------------
// 4-wave 128x128 GEMM, BK=32, LDS double-buffer, ONE barrier per K-step.
// A: bf16 [rows][KTOT] via global_load_lds (XOR-swizzled source, linear LDS).
// B: fp32 [KTOT][NB] reg-staged per thread as 4x4 micro-tile -> truncation
//    pack -> in-register transpose -> ds_write_b64 into pad-40 LDS with
//    phys_slot8B = kq ^ (n&6) (bijective; b128 reads stay contiguous).
// Schedule per step t: {issue B-loads(t+1), gl16 A(t+1)} -> frag reads ->
// MFMA -> write B(t+1) -> barrier.  (issue-early / write-late: B latency
// hides under compute; buf^1 is WAR-safe, its readers drained at t-1.)
// Grid: y = row-tile (slow, live-compact). FIRST: x = N-panel.
// !FIRST: x = panel*KSPLIT + z, koff = z*(KTOT/KSPLIT).
// ---------------------------------------------------------------------------
template <int KTOT, int NB, int KSPLIT, bool FIRST>
__global__ __launch_bounds__(256, 3) void k_gemm8(
    const ushort_t* __restrict__ A, const float* __restrict__ Bw,
    const int* __restrict__ meta, ushort_t* __restrict__ Obf) {
  constexpr int NKTT = KTOT / KSPLIT / BK;
  __shared__ short A_lds[2][128 * BK];      // 16 KB
  __shared__ short B_lds[2][128 * BSTR];    // 20 KB

  int bt = blockIdx.y;
  if (bt >= meta[24]) return;      // uniform exit before any barrier
  int e    = meta[64 + bt];
  int row0 = meta[128 + bt];
  int n0, koff, z;
  if constexpr (FIRST) {
    n0 = blockIdx.x * 128; koff = 0; z = 0;
  } else {
    n0 = (blockIdx.x / KSPLIT) * 128; z = blockIdx.x % KSPLIT;
    koff = z * (KTOT / KSPLIT);
  }

  int tid = threadIdx.x, lane = tid & 63, w = tid >> 6;
  int wr = w >> 1, wc = w & 1;

  // ---- A staging (global_load_lds, pre-swizzled source, linear dest) ----
  int srcSlot = (lane & 3) ^ ((lane >> 3) & 3);
  const ushort_t* aS = A + (size_t)(row0 + (tid >> 2)) * KTOT + koff + srcSlot * 8;
  int dstOff = w * 512;

#define STAGE_A(buf, kt)                                                      \
  do {                                                                        \
    gl16(aS + (size_t)(kt) * BK, &A_lds[buf][dstOff]);                        \
    gl16(aS + (size_t)(kt) * BK + (size_t)64 * KTOT,                          \
         &A_lds[buf][dstOff + 2048]);                                         \
  } while (0)

  // ---- B staging (fp32 reg-stage). thread: kq = tid>>5 (4 k's), nb =
  // tid&31 (4 n's). Loads: 4x dwordx4 (coalesced 512B/row-instr). ----
  int kq = tid >> 5, nb = tid & 31;
  const float* bS = Bw + (size_t)e * KTOT * NB + ((size_t)koff + kq * 4) * NB
                    + n0 + nb * 4;
  float4 bv0, bv1, bv2, bv3;

#define LOAD_B(kt)                                                            \
  do {                                                                        \
    const float* b0 = bS + (size_t)(kt) * BK * NB;                            \
    bv0 = *(const float4*)(b0);                                               \
    bv1 = *(const float4*)(b0 + NB);                                          \
    bv2 = *(const float4*)(b0 + 2 * NB);                                      \
    bv3 = *(const float4*)(b0 + 3 * NB);                                      \
  } while (0)

#define WRITE_B(buf)                                                          \
  do {                                                                        \
    _Pragma("unroll") for (int nn = 0; nn < 4; nn++) {                        \
      int n = nb * 4 + nn;                                                    \
      uint32 w0 = pkbf(((const float*)&bv0)[nn], ((const float*)&bv1)[nn]);   \
      uint32 w1 = pkbf(((const float*)&bv2)[nn], ((const float*)&bv3)[nn]);   \
      uint2* wp = (uint2*)&B_lds[buf][n * BSTR + ((kq ^ (n & 6)) << 2)];      \
      *wp = (uint2){w0, w1};                                                  \
    }                                                                         \
  } while (0)

  // ---- fragment read offsets ----
  int kslotRd = ((lane >> 4) ^ ((lane >> 1) & 3)) * 8;   // A (swizzled)
  int aOff[4], bOff[4];
#pragma unroll
  for (int m = 0; m < 4; m++)
    aOff[m] = (wr * 64 + m * 16 + (lane & 15)) * BK + kslotRd;
#pragma unroll
  for (int n = 0; n < 4; n++) {
    int col = wc * 64 + n * 16 + (lane & 15);
    bOff[n] = col * BSTR + (((lane >> 4) * 2) ^ (col & 6)) * 4;
  }

  f32x4 acc[4][4];
#pragma unroll
  for (int m = 0; m < 4; m++)
#pragma unroll
    for (int n = 0; n < 4; n++) acc[m][n] = (f32x4){0.f, 0.f, 0.f, 0.f};

  // prologue: tile 0 into buf 0
  LOAD_B(0);
  STAGE_A(0, 0);
  WRITE_B(0);
  __syncthreads();

#pragma unroll 2
  for (int t = 0; t < NKTT; ++t) {
    int cur = t & 1;
    if (t + 1 < NKTT) {
      LOAD_B(t + 1);               // issue early: latency under compute
      STAGE_A(cur ^ 1, t + 1);
    }
    const short* aB = A_lds[cur];
    const short* bB = B_lds[cur];
    short8 af[4], bf[4];
#pragma unroll
    for (int m = 0; m < 4; m++) af[m] = *(const short8*)&aB[aOff[m]];
#pragma unroll
    for (int n = 0; n < 4; n++) bf[n] = *(const short8*)&bB[bOff[n]];
    __builtin_amdgcn_s_setprio(1);
#pragma unroll
    for (int m = 0; m < 4; m++)
#pragma unroll
      for (int n = 0; n < 4; n++)
        acc[m][n] = MFMA(af[m], bf[n], acc[m][n], 0, 0, 0);
    __builtin_amdgcn_s_setprio(0);
    if (t + 1 < NKTT) WRITE_B(cur ^ 1);   // write late (after MFMAs)
    __syncthreads();                       // drains gl16 + ds writes
  }
#undef STAGE_A
#undef LOAD_B
#undef WRITE_B

  // C/D: col = lane&15, row = (lane>>4)*4 + r
  ushort_t* dst = FIRST ? Obf : Obf + (size_t)z * MAXR * NB;
#pragma unroll
  for (int m = 0; m < 4; m++) {
    int rowb = row0 + wr * 64 + m * 16 + (lane >> 4) * 4;
#pragma unroll
    for (int n = 0; n < 4; n++) {
      int col = n0 + wc * 64 + n * 16 + (lane & 15);
#pragma unroll
      for (int r = 0; r < 4; r++) {
        float v = acc[m][n][r];
        if (FIRST) v = v > 0.f ? v : 0.f;
        dst[(size_t)(rowb + r) * NB + col] = f2bf(v);
      }
    }
  }
}

// Reduce split-K partials, scale by prob, scatter to token rows.
__global__ __launch_bounds__(256) void k_reduce(
    const ushort_t* __restrict__ P, const int* __restrict__ meta,
    const int* __restrict__ perm, const float* __restrict__ prob_g,
    float* __restrict__ out) {
  int bt = blockIdx.y;
  if (bt >= meta[24]) return;
  int e = meta[64 + bt], row0 = meta[128 + bt], segEnd = meta[16 + e];
  int c0 = blockIdx.x * 64;
  int t = threadIdx.x;
  int col = c0 + (t & 7) * 8;
#pragma unroll
  for (int i = 0; i < 4; i++) {
    int r = row0 + (t >> 3) + i * 32;
    if (r >= segEnd) continue;
    int tok = perm[r];
    float p = prob_g[r];
    float s[8];
#pragma unroll
    for (int j = 0; j < 8; j++) s[j] = 0.f;
#pragma unroll
    for (int z = 0; z < KS2; z++) {
      short8 v = *(const short8*)&P[((size_t)z * MAXR + r) * DM + col];
#pragma unroll
      for (int j = 0; j < 8; j++) s[j] += bf2f((ushort_t)v[j]);
    }
    float4 o0 = {p * s[0], p * s[1], p * s[2], p * s[3]};
    float4 o1 = {p * s[4], p * s[5], p * s[6], p * s[7]};
    *(float4*)&out[(size_t)tok * DM + col] = o0;
    *(float4*)&out[(size_t)tok * DM + col + 4] = o1;
  }
}

extern "C" void kernel_launch(void* const* d_in, const int* in_sizes, int n_in,
                              void* d_out, int out_size, void* d_ws, size_t ws_size,
                              hipStream_t stream) {
  const float* X  = (const float*)d_in[0];
  const float* Wr = (const float*)d_in[1];
  const float* wi = (const float*)d_in[2];   // [8][768][3072] fp32
  const float* wo = (const float*)d_in[3];   // [8][3072][768] fp32

  float* out        = (float*)d_out;
  float* out_logits = out + (size_t)NTOK * DM;
  float* out_idx    = out_logits + (size_t)NTOK * NE;

  char* w = (char*)d_ws;
  int*      meta      = (int*)w;                    // 4 KiB
  int*      expert_of = (int*)(w + 4096);           // 16 KiB
  float*    prob      = (float*)(w + 20480);        // 16 KiB
  int*      perm      = (int*)(w + 36864);          // 24 KiB
  float*    prob_g    = (float*)(w + 61440);        // 24 KiB
  ushort_t* Xg        = (ushort_t*)(w + 131072);    // 5120*768 bf16 (7.9MB)
  ushort_t* H         = Xg + (size_t)MAXR * DM;     // 5120*3072 bf16 (31.5MB)
  ushort_t* P         = H + (size_t)MAXR * DF;      // 2*5120*768 bf16 (15.7MB)
  // total ws ~ 55 MB

  k_router<<<NTOK / 4, 256, 0, stream>>>(X, Wr, out_logits, out_idx,
                                         expert_of, prob);
  k_scan<<<1, 64, 0, stream>>>(expert_of, prob, meta, perm, prob_g);
  k_copy<<<dim3(TM / 4, MAXTILES), 256, 0, stream>>>(X, meta, perm, Xg);
  k_gemm8<DM, DF, 1, true><<<dim3(DF / 128, MAXTILES), 256, 0, stream>>>(
      Xg, wi, meta, H);
  k_gemm8<DF, DM, KS2, false><<<dim3((DM / 128) * KS2, MAXTILES), 256, 0, stream>>>(
      H, wo, meta, P);
  k_reduce<<<dim3(DM / 64, MAXTILES), 256, 0, stream>>>(P, meta, perm, prob_g, out);
}